// Round 10
// baseline (258.142 us; speedup 1.0000x reference)
//
#include <hip/hip_runtime.h>

typedef unsigned short u16;
typedef _Float16 f16;
typedef __attribute__((ext_vector_type(8))) _Float16 f16x8;
typedef __attribute__((ext_vector_type(2))) _Float16 f16x2;
typedef __attribute__((ext_vector_type(4))) float f32x4;

__device__ inline float nlrelu(float z) { return (z > 0.f) ? -z : -0.01f * z; }  // -leaky_relu
__device__ inline float4 score4(float4 a, float4 b) {
    return make_float4(nlrelu(a.x + b.x), nlrelu(a.y + b.y), nlrelu(a.z + b.z), nlrelu(a.w + b.w));
}
__device__ inline unsigned packdup(float w) {
    f16x2 p = (f16x2){(f16)w, (f16)w};
    return __builtin_bit_cast(unsigned, p);
}

// ---------------- K1: weight frags (fp16) + count+pos + cursor zero ----------------
__global__ __launch_bounds__(256) void k_initcnt(const float* __restrict__ Wh, const float* __restrict__ Wo,
                       f16* __restrict__ B1, f16* __restrict__ B2,
                       const int* __restrict__ src, int* __restrict__ counts, int* __restrict__ pos,
                       int* __restrict__ cursor, int E, int N) {
    const int b = blockIdx.x;
    if (b == 0 && threadIdx.x == 0) *cursor = 0;
    if (b < 128) {                       // W1 frag: 32768 elems
        int i = b * 256 + threadIdx.x;
        int j = i & 7, lane = (i >> 3) & 63, kg = (i >> 9) & 3, nt = i >> 11;
        int n = nt * 16 + (lane & 15);
        int k = kg * 32 + ((lane >> 4) << 3) + j;
        B1[i] = (f16)Wh[(n >> 6) * (128 * 64) + k * 64 + (n & 63)];
    } else if (b < 192) {                // W2 frag: 16384 elems
        int i = (b - 128) * 256 + threadIdx.x;
        int j = i & 7, lane = (i >> 3) & 63, kg = (i >> 9) & 7, nt = i >> 12;
        int n = nt * 16 + (lane & 15);
        int k = kg * 32 + ((lane >> 4) << 3) + j;
        B2[i] = (f16)Wo[k * 64 + n];
    } else {                             // count + position assignment, 4 chains in flight
        const int base = (b - 192) * 1024 + threadIdx.x;
#pragma unroll
        for (int j = 0; j < 4; j++) {
            int e = base + j * 256;
            if (e < E) {
                int s = src[e];
                s = ((unsigned)s < (unsigned)N) ? s : 0;
                pos[e] = atomicAdd(&counts[s], 1);
            }
        }
    }
}

// ---------------- single-pass scan with atomic-ticket block base ----------------
__global__ __launch_bounds__(1024) void scan_ticket(const int* __restrict__ counts, int* __restrict__ rowst,
                                                    int* __restrict__ cursor, int n) {
    const int t = threadIdx.x, lane = t & 63, w = t >> 6;
    __shared__ int wsum[16];
    __shared__ int sh_base;
    int i = blockIdx.x * 1024 + t;
    int v = (i < n) ? counts[i] : 0;
    int orig = v;
    for (int d = 1; d < 64; d <<= 1) { int x = __shfl_up(v, d); if (lane >= d) v += x; }
    if (lane == 63) wsum[w] = v;
    __syncthreads();
    if (t == 0) {
        int acc = 0;
        for (int j = 0; j < 16; j++) { int tmp = wsum[j]; wsum[j] = acc; acc += tmp; }
        sh_base = atomicAdd(cursor, acc);       // claim this block's segment
    }
    __syncthreads();
    if (i < n) rowst[i] = sh_base + wsum[w] + (v - orig);
}

// ---------------- scatter WITHOUT atomics ----------------
__global__ __launch_bounds__(256) void scatter_noat(const int* __restrict__ src, const int* __restrict__ dst,
                                                    const int* __restrict__ rowst, const int* __restrict__ pos,
                                                    int* __restrict__ edged, int E, int N) {
    const int base = blockIdx.x * 1024 + threadIdx.x;
#pragma unroll
    for (int j = 0; j < 4; j++) {
        int e = base + j * 256;
        if (e < E) {
            int s = src[e];
            s = ((unsigned)s < (unsigned)N) ? s : 0;
            int d = dst[e];
            d = ((unsigned)d < (unsigned)N) ? d : 0;
            edged[rowst[s] + pos[e]] = d;
        }
    }
}

// ---------------- gemm1 (f16 MFMA): H1[Mx256] = X[Mx128] @ W1^T, fused s1/s2 ----------------
__global__ __launch_bounds__(256) void gemm1_f16(const float* __restrict__ X, const f16* __restrict__ B1,
        const float* __restrict__ attnH,
        f16* __restrict__ H1, float* __restrict__ s1, float* __restrict__ s2, int M) {
    const int lane = threadIdx.x & 63, wave = threadIdx.x >> 6;
    const int row0 = (blockIdx.x * 4 + wave) * 16;
    if (row0 >= M) return;
    const int mrow = row0 + (lane & 15);
    const int koff = (lane >> 4) * 8;
    const float* aptr = X + (size_t)mrow * 128 + koff;

    f32x4 acc[16];
#pragma unroll
    for (int c = 0; c < 16; c++) acc[c] = (f32x4){0.f, 0.f, 0.f, 0.f};

#pragma unroll
    for (int kg = 0; kg < 4; kg++) {
        float av[8];
        *(float4*)av       = *(const float4*)(aptr + kg * 32);
        *(float4*)(av + 4) = *(const float4*)(aptr + kg * 32 + 4);
        f16x8 a;
#pragma unroll
        for (int j = 0; j < 8; j++) a[j] = (f16)av[j];
#pragma unroll
        for (int nt = 0; nt < 16; nt++) {
            const size_t bidx = (size_t)(((nt << 2) + kg) * 64 + lane) * 8;
            f16x8 bfr = *(const f16x8*)(B1 + bidx);
            acc[nt] = __builtin_amdgcn_mfma_f32_16x16x32_f16(a, bfr, acc[nt], 0, 0, 0);
        }
    }
    const int rbase = (lane >> 4) * 4;
    const int colq = lane & 15;
#pragma unroll
    for (int h = 0; h < 4; h++) {
        float s1a[4] = {0.f, 0.f, 0.f, 0.f}, s2a[4] = {0.f, 0.f, 0.f, 0.f};
#pragma unroll
        for (int q = 0; q < 4; q++) {
            const int nt = h * 4 + q;
            const int col = nt * 16 + colq;
            const float a1v = attnH[h * 128 + (col & 63)];
            const float a2v = attnH[h * 128 + 64 + (col & 63)];
#pragma unroll
            for (int r = 0; r < 4; r++) {
                float c = acc[nt][r];
                H1[(size_t)(row0 + rbase + r) * 256 + col] = (f16)c;
                s1a[r] += c * a1v;
                s2a[r] += c * a2v;
            }
        }
#pragma unroll
        for (int off = 1; off < 16; off <<= 1)
#pragma unroll
            for (int r = 0; r < 4; r++) {
                s1a[r] += __shfl_xor(s1a[r], off);
                s2a[r] += __shfl_xor(s2a[r], off);
            }
        if (colq == 0)
#pragma unroll
            for (int r = 0; r < 4; r++) {
                s1[(size_t)(row0 + rbase + r) * 4 + h] = s1a[r];
                s2[(size_t)(row0 + rbase + r) * 4 + h] = s2a[r];
            }
    }
}

// ---------------- gemm2 (f16 MFMA): H2[Mx64] = hcat[Mx256] @ W2^T, fused s1b/s2b ----------------
__global__ __launch_bounds__(256) void gemm2_f16(const f16* __restrict__ Hc, const f16* __restrict__ B2,
        const float* __restrict__ attnO,
        f16* __restrict__ H2, float* __restrict__ s1b, float* __restrict__ s2b, int M) {
    const int lane = threadIdx.x & 63, wave = threadIdx.x >> 6;
    const int row0 = (blockIdx.x * 4 + wave) * 16;
    if (row0 >= M) return;
    const int mrow = row0 + (lane & 15);
    const int koff = (lane >> 4) * 8;
    const f16* ap = Hc + (size_t)mrow * 256 + koff;

    f32x4 acc[4];
#pragma unroll
    for (int c = 0; c < 4; c++) acc[c] = (f32x4){0.f, 0.f, 0.f, 0.f};

#pragma unroll
    for (int kg = 0; kg < 8; kg++) {
        f16x8 a = *(const f16x8*)(ap + kg * 32);
#pragma unroll
        for (int nt = 0; nt < 4; nt++) {
            const size_t bidx = (size_t)(((nt << 3) + kg) * 64 + lane) * 8;
            f16x8 bfr = *(const f16x8*)(B2 + bidx);
            acc[nt] = __builtin_amdgcn_mfma_f32_16x16x32_f16(a, bfr, acc[nt], 0, 0, 0);
        }
    }
    const int rbase = (lane >> 4) * 4;
    const int colq = lane & 15;
    float s1a[4] = {0.f, 0.f, 0.f, 0.f}, s2a[4] = {0.f, 0.f, 0.f, 0.f};
#pragma unroll
    for (int nt = 0; nt < 4; nt++) {
        const int col = nt * 16 + colq;
        const float a1v = attnO[col];
        const float a2v = attnO[64 + col];
#pragma unroll
        for (int r = 0; r < 4; r++) {
            float c = acc[nt][r];
            H2[(size_t)(row0 + rbase + r) * 64 + col] = (f16)c;
            s1a[r] += c * a1v;
            s2a[r] += c * a2v;
        }
    }
#pragma unroll
    for (int off = 1; off < 16; off <<= 1)
#pragma unroll
        for (int r = 0; r < 4; r++) {
            s1a[r] += __shfl_xor(s1a[r], off);
            s2a[r] += __shfl_xor(s2a[r], off);
        }
    if (colq == 0)
#pragma unroll
        for (int r = 0; r < 4; r++) {
            s1b[row0 + rbase + r] = s1a[r];
            s2b[row0 + rbase + r] = s2a[r];
        }
}

// ---------------- layer-1 aggregate: one wave per node; PAIRED gather (2 edges/instr) ----------------
__global__ __launch_bounds__(256) void agg_l1(const int* __restrict__ rowst, const int* __restrict__ cnt,
                                              const int* __restrict__ edged,
                                              const float* __restrict__ s1, const float* __restrict__ s2,
                                              const f16* __restrict__ H, f16* __restrict__ hcat, int N) {
    __shared__ unsigned wls[4][64][4];
    __shared__ int dls[4][64];
    const int t = threadIdx.x, lane = t & 63, wave = t >> 6;
    const int node = blockIdx.x * 4 + wave;
    if (node >= N) return;
    const int beg = rowst[node];
    const int deg = cnt[node];
    const int end = beg + deg;
    if (deg == 0) {
        *(uint2*)(hcat + (size_t)node * 256 + lane * 4) = make_uint2(0u, 0u);
        return;
    }
    const float4 s1v = *(const float4*)(s1 + (size_t)node * 4);

    if (deg <= 64) {
        int d = 0;
        if (lane < deg) d = edged[beg + lane];
        dls[wave][lane] = d;
        float4 s2v = *(const float4*)(s2 + (size_t)d * 4);
        float4 sc = score4(s1v, s2v);
        if (lane >= deg) sc = make_float4(-3e38f, -3e38f, -3e38f, -3e38f);
        float4 m = sc;
#pragma unroll
        for (int off = 32; off > 0; off >>= 1) {
            m.x = fmaxf(m.x, __shfl_xor(m.x, off));
            m.y = fmaxf(m.y, __shfl_xor(m.y, off));
            m.z = fmaxf(m.z, __shfl_xor(m.z, off));
            m.w = fmaxf(m.w, __shfl_xor(m.w, off));
        }
        float4 ex = make_float4(0.f, 0.f, 0.f, 0.f);
        if (lane < deg) ex = make_float4(__expf(sc.x - m.x), __expf(sc.y - m.y),
                                         __expf(sc.z - m.z), __expf(sc.w - m.w));
        float4 sm = ex;
#pragma unroll
        for (int off = 32; off > 0; off >>= 1) {
            sm.x += __shfl_xor(sm.x, off);
            sm.y += __shfl_xor(sm.y, off);
            sm.z += __shfl_xor(sm.z, off);
            sm.w += __shfl_xor(sm.w, off);
        }
        wls[wave][lane][0] = packdup(ex.x / sm.x);   // 0 for lane >= deg
        wls[wave][lane][1] = packdup(ex.y / sm.y);
        wls[wave][lane][2] = packdup(ex.z / sm.z);
        wls[wave][lane][3] = packdup(ex.w / sm.w);
        // ---- paired phase B: lanes 0-31 = edge e, lanes 32-63 = edge e+1; 16B/lane ----
        const int h2 = lane >> 5;          // which edge of the pair
        const int p = lane & 31;           // feature-octet index (features p*8 .. p*8+7)
        const int headp = p >> 3;
        f16x2 a0[4], a1[4];
#pragma unroll
        for (int j = 0; j < 4; j++) { a0[j] = (f16x2)(f16)0.f; a1[j] = (f16x2)(f16)0.f; }
        for (int e = 0; e < deg; e += 2) {
            int ei = e + h2;                       // ei <= 63 always (phantom has weight 0)
            int dd = dls[wave][ei];
            f16x2 w2 = __builtin_bit_cast(f16x2, wls[wave][ei][headp]);
            uint4 raw = *(const uint4*)(H + (size_t)dd * 256 + p * 8);
            if ((e >> 1) & 1) {
                a1[0] += w2 * __builtin_bit_cast(f16x2, raw.x);
                a1[1] += w2 * __builtin_bit_cast(f16x2, raw.y);
                a1[2] += w2 * __builtin_bit_cast(f16x2, raw.z);
                a1[3] += w2 * __builtin_bit_cast(f16x2, raw.w);
            } else {
                a0[0] += w2 * __builtin_bit_cast(f16x2, raw.x);
                a0[1] += w2 * __builtin_bit_cast(f16x2, raw.y);
                a0[2] += w2 * __builtin_bit_cast(f16x2, raw.z);
                a0[3] += w2 * __builtin_bit_cast(f16x2, raw.w);
            }
        }
        float r[8];
#pragma unroll
        for (int j = 0; j < 4; j++) {
            r[2 * j]     = (float)a0[j][0] + (float)a1[j][0];
            r[2 * j + 1] = (float)a0[j][1] + (float)a1[j][1];
        }
#pragma unroll
        for (int k = 0; k < 8; k++) r[k] += __shfl_xor(r[k], 32);   // combine edge halves
        if (lane < 32) {
            uint4 o;
            unsigned* op = &o.x;
#pragma unroll
            for (int j = 0; j < 4; j++) {
                float v0 = r[2 * j], v1 = r[2 * j + 1];
                v0 = (v0 > 0.f) ? v0 : (__expf(v0) - 1.f);
                v1 = (v1 > 0.f) ? v1 : (__expf(v1) - 1.f);
                f16x2 pk = (f16x2){(f16)v0, (f16)v1};
                op[j] = __builtin_bit_cast(unsigned, pk);
            }
            *(uint4*)(hcat + (size_t)node * 256 + p * 8) = o;
        }
    } else {
        // generic slow path (deg > 64), fp32 math, per-edge gather
        const int head = lane >> 4;
        float4 m = make_float4(-3e38f, -3e38f, -3e38f, -3e38f);
        for (int e = beg + lane; e < end; e += 64) {
            int d = edged[e];
            float4 sc = score4(s1v, *(const float4*)(s2 + (size_t)d * 4));
            m.x = fmaxf(m.x, sc.x); m.y = fmaxf(m.y, sc.y); m.z = fmaxf(m.z, sc.z); m.w = fmaxf(m.w, sc.w);
        }
#pragma unroll
        for (int off = 32; off > 0; off >>= 1) {
            m.x = fmaxf(m.x, __shfl_xor(m.x, off));
            m.y = fmaxf(m.y, __shfl_xor(m.y, off));
            m.z = fmaxf(m.z, __shfl_xor(m.z, off));
            m.w = fmaxf(m.w, __shfl_xor(m.w, off));
        }
        float4 sm = make_float4(0.f, 0.f, 0.f, 0.f);
        for (int e = beg + lane; e < end; e += 64) {
            int d = edged[e];
            float4 sc = score4(s1v, *(const float4*)(s2 + (size_t)d * 4));
            sm.x += __expf(sc.x - m.x); sm.y += __expf(sc.y - m.y);
            sm.z += __expf(sc.z - m.z); sm.w += __expf(sc.w - m.w);
        }
#pragma unroll
        for (int off = 32; off > 0; off >>= 1) {
            sm.x += __shfl_xor(sm.x, off);
            sm.y += __shfl_xor(sm.y, off);
            sm.z += __shfl_xor(sm.z, off);
            sm.w += __shfl_xor(sm.w, off);
        }
        float4 inv = make_float4(1.f / sm.x, 1.f / sm.y, 1.f / sm.z, 1.f / sm.w);
        float4 acc = make_float4(0.f, 0.f, 0.f, 0.f);
        for (int e = beg; e < end; e++) {
            int dd = edged[e];
            float4 sc = score4(s1v, *(const float4*)(s2 + (size_t)dd * 4));
            float wv[4] = { __expf(sc.x - m.x) * inv.x, __expf(sc.y - m.y) * inv.y,
                            __expf(sc.z - m.z) * inv.z, __expf(sc.w - m.w) * inv.w };
            float w = (head == 0) ? wv[0] : (head == 1) ? wv[1] : (head == 2) ? wv[2] : wv[3];
            const f16* hp = H + (size_t)dd * 256 + lane * 4;
            acc.x += w * (float)hp[0]; acc.y += w * (float)hp[1];
            acc.z += w * (float)hp[2]; acc.w += w * (float)hp[3];
        }
        acc.x = (acc.x > 0.f) ? acc.x : (__expf(acc.x) - 1.f);
        acc.y = (acc.y > 0.f) ? acc.y : (__expf(acc.y) - 1.f);
        acc.z = (acc.z > 0.f) ? acc.z : (__expf(acc.z) - 1.f);
        acc.w = (acc.w > 0.f) ? acc.w : (__expf(acc.w) - 1.f);
        f16x2 o0 = (f16x2){(f16)acc.x, (f16)acc.y};
        f16x2 o1 = (f16x2){(f16)acc.z, (f16)acc.w};
        *(uint2*)(hcat + (size_t)node * 256 + lane * 4) =
            make_uint2(__builtin_bit_cast(unsigned, o0), __builtin_bit_cast(unsigned, o1));
    }
}

// ---------------- layer-2 aggregate: PAIRED gather (2 edges/instr, 2 features/lane) ----------------
__global__ __launch_bounds__(256) void agg_l2(const int* __restrict__ rowst, const int* __restrict__ cnt,
                                              const int* __restrict__ edged,
                                              const float* __restrict__ s1, const float* __restrict__ s2,
                                              const f16* __restrict__ H, float* __restrict__ outp, int N) {
    __shared__ float wls[4][64];
    __shared__ int dls[4][64];
    const int t = threadIdx.x, lane = t & 63, wave = t >> 6;
    const int node = blockIdx.x * 4 + wave;
    if (node >= N) return;
    const int beg = rowst[node];
    const int deg = cnt[node];
    const int end = beg + deg;
    if (deg == 0) { outp[(size_t)node * 64 + lane] = 0.f; return; }
    const float s1v = s1[node];

    if (deg <= 64) {
        int d = 0;
        if (lane < deg) d = edged[beg + lane];
        dls[wave][lane] = d;
        float z = s1v + s2[d];
        float sc = (lane < deg) ? nlrelu(z) : -3e38f;
        float m = sc;
#pragma unroll
        for (int off = 32; off > 0; off >>= 1) m = fmaxf(m, __shfl_xor(m, off));
        float ex = (lane < deg) ? __expf(sc - m) : 0.f;
        float sm = ex;
#pragma unroll
        for (int off = 32; off > 0; off >>= 1) sm += __shfl_xor(sm, off);
        wls[wave][lane] = ex / sm;                 // 0 for lane >= deg
        // paired gather: lanes 0-31 = edge e, lanes 32-63 = edge e+1; 4B (2 features)/lane
        const int h2 = lane >> 5;
        const int p = lane & 31;
        float ax = 0.f, ay = 0.f;
        for (int e = 0; e < deg; e += 2) {
            int ei = e + h2;
            float w = wls[wave][ei];
            int dd = dls[wave][ei];
            unsigned raw = *(const unsigned*)(H + (size_t)dd * 64 + p * 2);
            f16x2 hv = __builtin_bit_cast(f16x2, raw);
            ax += w * (float)hv[0];
            ay += w * (float)hv[1];
        }
        ax += __shfl_xor(ax, 32);
        ay += __shfl_xor(ay, 32);
        if (lane < 32) *(float2*)(outp + (size_t)node * 64 + p * 2) = make_float2(ax, ay);
    } else {
        float m = -3e38f;
        for (int e = beg + lane; e < end; e += 64) {
            int d = edged[e];
            m = fmaxf(m, nlrelu(s1v + s2[d]));
        }
#pragma unroll
        for (int off = 32; off > 0; off >>= 1) m = fmaxf(m, __shfl_xor(m, off));
        float sm = 0.f;
        for (int e = beg + lane; e < end; e += 64) {
            int d = edged[e];
            sm += __expf(nlrelu(s1v + s2[d]) - m);
        }
#pragma unroll
        for (int off = 32; off > 0; off >>= 1) sm += __shfl_xor(sm, off);
        float inv = 1.f / sm;
        float acc = 0.f;
        for (int e = beg; e < end; e++) {
            int dd = edged[e];
            float w = __expf(nlrelu(s1v + s2[dd]) - m) * inv;
            acc += w * (float)H[(size_t)dd * 64 + lane];
        }
        outp[(size_t)node * 64 + lane] = acc;
    }
}

extern "C" void kernel_launch(void* const* d_in, const int* in_sizes, int n_in,
                              void* d_out, int out_size, void* d_ws, size_t ws_size,
                              hipStream_t stream) {
    const float* x     = (const float*)d_in[0];
    const int*   ei    = (const int*)d_in[1];     // [2][E] int32
    const float* Wh    = (const float*)d_in[2];
    const float* attnH = (const float*)d_in[3];
    const float* Wo    = (const float*)d_in[4];
    const float* attnO = (const float*)d_in[5];
    float* out         = (float*)d_out;

    const int N = in_sizes[0] / 128;    // 50000
    const int E = in_sizes[1] / 2;      // 800000
    const int* srcp = ei;
    const int* dstp = ei + E;

    char* base = (char*)d_ws;
    size_t off = 0;
    auto take = [&](size_t b) { void* p = base + off; off += (b + 255) & ~(size_t)255; return p; };
    f16*   B1     = (f16*)  take(32768 * 2);
    f16*   B2     = (f16*)  take(16384 * 2);
    int*   counts = (int*)  take((size_t)N * 4);
    int*   rowst  = (int*)  take((size_t)N * 4);
    int*   pos    = (int*)  take((size_t)E * 4);
    int*   edged  = (int*)  take((size_t)E * 4);
    int*   cursor = (int*)  take(256);
    float* s1     = (float*)take((size_t)N * 4 * 4);
    float* s2     = (float*)take((size_t)N * 4 * 4);
    float* s1b    = (float*)take((size_t)N * 4);
    float* s2b    = (float*)take((size_t)N * 4);
    f16*   H1     = (f16*)  take((size_t)N * 256 * 2);
    f16*   hcat   = (f16*)  take((size_t)N * 256 * 2);
    f16*   H2     = (f16*)  take((size_t)N * 64 * 2);

    hipMemsetAsync(counts, 0, (size_t)N * 4, stream);

    const int eb4 = (E + 1023) / 1024;
    k_initcnt<<<192 + eb4, 256, 0, stream>>>(Wh, Wo, B1, B2, srcp, counts, pos, cursor, E, N);

    const int nb = (N + 1023) / 1024;
    scan_ticket<<<nb, 1024, 0, stream>>>(counts, rowst, cursor, N);

    scatter_noat<<<eb4, 256, 0, stream>>>(srcp, dstp, rowst, pos, edged, E, N);

    const int Gg = (N + 63) / 64;
    gemm1_f16<<<Gg, 256, 0, stream>>>(x, B1, attnH, H1, s1, s2, N);
    agg_l1<<<(N + 3) / 4, 256, 0, stream>>>(rowst, counts, edged, s1, s2, H1, hcat, N);
    gemm2_f16<<<Gg, 256, 0, stream>>>(hcat, B2, attnO, H2, s1b, s2b, N);
    agg_l2<<<(N + 3) / 4, 256, 0, stream>>>(rowst, counts, edged, s1b, s2b, H2, out, N);
}

// Round 11
// 243.423 us; speedup vs baseline: 1.0605x; 1.0605x over previous
//
#include <hip/hip_runtime.h>

typedef _Float16 f16;
typedef __attribute__((ext_vector_type(8))) _Float16 f16x8;
typedef __attribute__((ext_vector_type(2))) _Float16 f16x2;
typedef __attribute__((ext_vector_type(4))) float f32x4;

__device__ inline float nlrelu(float z) { return (z > 0.f) ? -z : -0.01f * z; }  // -leaky_relu
__device__ inline float4 score4(float4 a, float4 b) {
    return make_float4(nlrelu(a.x + b.x), nlrelu(a.y + b.y), nlrelu(a.z + b.z), nlrelu(a.w + b.w));
}
__device__ inline unsigned packdup(float w) {
    f16x2 p = (f16x2){(f16)w, (f16)w};
    return __builtin_bit_cast(unsigned, p);
}

// ---------------- K1: weight frags (fp16) + count+pos + cursor zero ----------------
__global__ __launch_bounds__(256) void k_initcnt(const float* __restrict__ Wh, const float* __restrict__ Wo,
                       f16* __restrict__ B1, f16* __restrict__ B2,
                       const int* __restrict__ src, int* __restrict__ counts, int* __restrict__ pos,
                       int* __restrict__ cursor, int E, int N) {
    const int b = blockIdx.x;
    if (b == 0 && threadIdx.x == 0) *cursor = 0;
    if (b < 128) {                       // W1 frag: 32768 elems
        int i = b * 256 + threadIdx.x;
        int j = i & 7, lane = (i >> 3) & 63, kg = (i >> 9) & 3, nt = i >> 11;
        int n = nt * 16 + (lane & 15);
        int k = kg * 32 + ((lane >> 4) << 3) + j;
        B1[i] = (f16)Wh[(n >> 6) * (128 * 64) + k * 64 + (n & 63)];
    } else if (b < 192) {                // W2 frag: 16384 elems
        int i = (b - 128) * 256 + threadIdx.x;
        int j = i & 7, lane = (i >> 3) & 63, kg = (i >> 9) & 7, nt = i >> 12;
        int n = nt * 16 + (lane & 15);
        int k = kg * 32 + ((lane >> 4) << 3) + j;
        B2[i] = (f16)Wo[k * 64 + n];
    } else {                             // count + position assignment, 4 chains in flight
        const int base = (b - 192) * 1024 + threadIdx.x;
#pragma unroll
        for (int j = 0; j < 4; j++) {
            int e = base + j * 256;
            if (e < E) {
                int s = src[e];
                s = ((unsigned)s < (unsigned)N) ? s : 0;
                pos[e] = atomicAdd(&counts[s], 1);
            }
        }
    }
}

// ---------------- single-pass scan with atomic-ticket block base ----------------
__global__ __launch_bounds__(1024) void scan_ticket(const int* __restrict__ counts, int* __restrict__ rowst,
                                                    int* __restrict__ cursor, int n) {
    const int t = threadIdx.x, lane = t & 63, w = t >> 6;
    __shared__ int wsum[16];
    __shared__ int sh_base;
    int i = blockIdx.x * 1024 + t;
    int v = (i < n) ? counts[i] : 0;
    int orig = v;
    for (int d = 1; d < 64; d <<= 1) { int x = __shfl_up(v, d); if (lane >= d) v += x; }
    if (lane == 63) wsum[w] = v;
    __syncthreads();
    if (t == 0) {
        int acc = 0;
        for (int j = 0; j < 16; j++) { int tmp = wsum[j]; wsum[j] = acc; acc += tmp; }
        sh_base = atomicAdd(cursor, acc);
    }
    __syncthreads();
    if (i < n) rowst[i] = sh_base + wsum[w] + (v - orig);
}

// ---------------- K3: scatter (no atomics) + gemm1 (f16 MFMA, fused s1/s2) ----------------
// blocks [0, Gs): scatter; [Gs, Gs+Gg): gemm1. Scatter first so its long pole starts early.
__global__ __launch_bounds__(256) void k_scatg1(
        const int* __restrict__ src, const int* __restrict__ dst,
        const int* __restrict__ rowst, const int* __restrict__ pos, int* __restrict__ edged,
        const float* __restrict__ X, const f16* __restrict__ B1, const float* __restrict__ attnH,
        f16* __restrict__ H1, float* __restrict__ s1, float* __restrict__ s2,
        int M, int E, int N, int Gs) {
    if ((int)blockIdx.x < Gs) {
        const int base = blockIdx.x * 1024 + threadIdx.x;
#pragma unroll
        for (int j = 0; j < 4; j++) {
            int e = base + j * 256;
            if (e < E) {
                int s = src[e];
                s = ((unsigned)s < (unsigned)N) ? s : 0;
                int d = dst[e];
                d = ((unsigned)d < (unsigned)N) ? d : 0;
                edged[rowst[s] + pos[e]] = d;
            }
        }
        return;
    }
    const int gb = blockIdx.x - Gs;
    const int lane = threadIdx.x & 63, wave = threadIdx.x >> 6;
    const int row0 = (gb * 4 + wave) * 16;
    if (row0 >= M) return;
    const int mrow = row0 + (lane & 15);
    const int koff = (lane >> 4) * 8;
    const float* aptr = X + (size_t)mrow * 128 + koff;

    f32x4 acc[16];
#pragma unroll
    for (int c = 0; c < 16; c++) acc[c] = (f32x4){0.f, 0.f, 0.f, 0.f};

#pragma unroll
    for (int kg = 0; kg < 4; kg++) {
        float av[8];
        *(float4*)av       = *(const float4*)(aptr + kg * 32);
        *(float4*)(av + 4) = *(const float4*)(aptr + kg * 32 + 4);
        f16x8 a;
#pragma unroll
        for (int j = 0; j < 8; j++) a[j] = (f16)av[j];
#pragma unroll
        for (int nt = 0; nt < 16; nt++) {
            const size_t bidx = (size_t)(((nt << 2) + kg) * 64 + lane) * 8;
            f16x8 bfr = *(const f16x8*)(B1 + bidx);
            acc[nt] = __builtin_amdgcn_mfma_f32_16x16x32_f16(a, bfr, acc[nt], 0, 0, 0);
        }
    }
    const int rbase = (lane >> 4) * 4;
    const int colq = lane & 15;
#pragma unroll
    for (int h = 0; h < 4; h++) {
        float s1a[4] = {0.f, 0.f, 0.f, 0.f}, s2a[4] = {0.f, 0.f, 0.f, 0.f};
#pragma unroll
        for (int q = 0; q < 4; q++) {
            const int nt = h * 4 + q;
            const int col = nt * 16 + colq;
            const float a1v = attnH[h * 128 + (col & 63)];
            const float a2v = attnH[h * 128 + 64 + (col & 63)];
#pragma unroll
            for (int r = 0; r < 4; r++) {
                float c = acc[nt][r];
                H1[(size_t)(row0 + rbase + r) * 256 + col] = (f16)c;
                s1a[r] += c * a1v;
                s2a[r] += c * a2v;
            }
        }
#pragma unroll
        for (int off = 1; off < 16; off <<= 1)
#pragma unroll
            for (int r = 0; r < 4; r++) {
                s1a[r] += __shfl_xor(s1a[r], off);
                s2a[r] += __shfl_xor(s2a[r], off);
            }
        if (colq == 0)
#pragma unroll
            for (int r = 0; r < 4; r++) {
                s1[(size_t)(row0 + rbase + r) * 4 + h] = s1a[r];
                s2[(size_t)(row0 + rbase + r) * 4 + h] = s2a[r];
            }
    }
}

// ---------------- agg_l1 + gemm2 fused: 16 nodes/block (4/wave serial), hcat in LDS ----------------
__global__ __launch_bounds__(256) void agg1g2(
        const int* __restrict__ rowst, const int* __restrict__ cnt, const int* __restrict__ edged,
        const float* __restrict__ s1, const float* __restrict__ s2, const f16* __restrict__ H,
        const f16* __restrict__ B2, const float* __restrict__ attnO,
        f16* __restrict__ H2, float* __restrict__ s1b, float* __restrict__ s2b, int N) {
    __shared__ unsigned wls[4][64][4];
    __shared__ int dls[4][64];
    __shared__ f16 hc[16][264];          // padded rows: 264*2=528 B (16-B mult, breaks pow2 stride)
    const int t = threadIdx.x, lane = t & 63, wave = t >> 6;
    const int nbase = blockIdx.x * 16 + wave * 4;

    for (int i = 0; i < 4; i++) {
        const int node = nbase + i;
        const int slot = wave * 4 + i;
        if (node >= N) { *(uint2*)&hc[slot][lane * 4] = make_uint2(0u, 0u); continue; }
        const int beg = rowst[node];
        const int deg = cnt[node];
        if (deg == 0) { *(uint2*)&hc[slot][lane * 4] = make_uint2(0u, 0u); continue; }
        const float4 s1v = *(const float4*)(s1 + (size_t)node * 4);

        if (deg <= 64) {
            int d = 0;
            if (lane < deg) d = edged[beg + lane];
            dls[wave][lane] = d;
            float4 s2v = *(const float4*)(s2 + (size_t)d * 4);
            float4 sc = score4(s1v, s2v);
            float4 ex = make_float4(0.f, 0.f, 0.f, 0.f);
            if (lane < deg) ex = make_float4(__expf(sc.x), __expf(sc.y), __expf(sc.z), __expf(sc.w));
            float4 sm = ex;
#pragma unroll
            for (int off = 32; off > 0; off >>= 1) {
                sm.x += __shfl_xor(sm.x, off);
                sm.y += __shfl_xor(sm.y, off);
                sm.z += __shfl_xor(sm.z, off);
                sm.w += __shfl_xor(sm.w, off);
            }
            wls[wave][lane][0] = packdup(ex.x / sm.x);
            wls[wave][lane][1] = packdup(ex.y / sm.y);
            wls[wave][lane][2] = packdup(ex.z / sm.z);
            wls[wave][lane][3] = packdup(ex.w / sm.w);
            // paired phase B: lanes 0-31 edge e, 32-63 edge e+1; 16 B/lane
            const int h2 = lane >> 5;
            const int p = lane & 31;
            const int headp = p >> 3;
            f16x2 a0[4], a1[4];
#pragma unroll
            for (int j = 0; j < 4; j++) { a0[j] = (f16x2)(f16)0.f; a1[j] = (f16x2)(f16)0.f; }
            for (int e = 0; e < deg; e += 2) {
                int ei = e + h2;
                int dd = dls[wave][ei];
                f16x2 w2 = __builtin_bit_cast(f16x2, wls[wave][ei][headp]);
                uint4 raw = *(const uint4*)(H + (size_t)dd * 256 + p * 8);
                if ((e >> 1) & 1) {
                    a1[0] += w2 * __builtin_bit_cast(f16x2, raw.x);
                    a1[1] += w2 * __builtin_bit_cast(f16x2, raw.y);
                    a1[2] += w2 * __builtin_bit_cast(f16x2, raw.z);
                    a1[3] += w2 * __builtin_bit_cast(f16x2, raw.w);
                } else {
                    a0[0] += w2 * __builtin_bit_cast(f16x2, raw.x);
                    a0[1] += w2 * __builtin_bit_cast(f16x2, raw.y);
                    a0[2] += w2 * __builtin_bit_cast(f16x2, raw.z);
                    a0[3] += w2 * __builtin_bit_cast(f16x2, raw.w);
                }
            }
            float r[8];
#pragma unroll
            for (int j = 0; j < 4; j++) {
                r[2 * j]     = (float)a0[j][0] + (float)a1[j][0];
                r[2 * j + 1] = (float)a0[j][1] + (float)a1[j][1];
            }
#pragma unroll
            for (int k = 0; k < 8; k++) r[k] += __shfl_xor(r[k], 32);
            if (lane < 32) {
                uint4 o;
                unsigned* op = &o.x;
#pragma unroll
                for (int j = 0; j < 4; j++) {
                    float v0 = r[2 * j], v1 = r[2 * j + 1];
                    v0 = (v0 > 0.f) ? v0 : (__expf(v0) - 1.f);
                    v1 = (v1 > 0.f) ? v1 : (__expf(v1) - 1.f);
                    f16x2 pk = (f16x2){(f16)v0, (f16)v1};
                    op[j] = __builtin_bit_cast(unsigned, pk);
                }
                *(uint4*)&hc[slot][p * 8] = o;
            }
        } else {
            // slow path (deg > 64), fp32, no-max
            const int end = beg + deg;
            const int head = lane >> 4;
            float4 sm = make_float4(0.f, 0.f, 0.f, 0.f);
            for (int e = beg + lane; e < end; e += 64) {
                int d = edged[e];
                float4 sc = score4(s1v, *(const float4*)(s2 + (size_t)d * 4));
                sm.x += __expf(sc.x); sm.y += __expf(sc.y);
                sm.z += __expf(sc.z); sm.w += __expf(sc.w);
            }
#pragma unroll
            for (int off = 32; off > 0; off >>= 1) {
                sm.x += __shfl_xor(sm.x, off);
                sm.y += __shfl_xor(sm.y, off);
                sm.z += __shfl_xor(sm.z, off);
                sm.w += __shfl_xor(sm.w, off);
            }
            float4 inv = make_float4(1.f / sm.x, 1.f / sm.y, 1.f / sm.z, 1.f / sm.w);
            float4 acc = make_float4(0.f, 0.f, 0.f, 0.f);
            for (int e = beg; e < end; e++) {
                int dd = edged[e];
                float4 sc = score4(s1v, *(const float4*)(s2 + (size_t)dd * 4));
                float wv[4] = { __expf(sc.x) * inv.x, __expf(sc.y) * inv.y,
                                __expf(sc.z) * inv.z, __expf(sc.w) * inv.w };
                float w = (head == 0) ? wv[0] : (head == 1) ? wv[1] : (head == 2) ? wv[2] : wv[3];
                const f16* hp = H + (size_t)dd * 256 + lane * 4;
                acc.x += w * (float)hp[0]; acc.y += w * (float)hp[1];
                acc.z += w * (float)hp[2]; acc.w += w * (float)hp[3];
            }
            acc.x = (acc.x > 0.f) ? acc.x : (__expf(acc.x) - 1.f);
            acc.y = (acc.y > 0.f) ? acc.y : (__expf(acc.y) - 1.f);
            acc.z = (acc.z > 0.f) ? acc.z : (__expf(acc.z) - 1.f);
            acc.w = (acc.w > 0.f) ? acc.w : (__expf(acc.w) - 1.f);
            f16x2 o0 = (f16x2){(f16)acc.x, (f16)acc.y};
            f16x2 o1 = (f16x2){(f16)acc.z, (f16)acc.w};
            *(uint2*)&hc[slot][lane * 4] =
                make_uint2(__builtin_bit_cast(unsigned, o0), __builtin_bit_cast(unsigned, o1));
        }
    }
    __syncthreads();
    // ---- gemm2 for this block's 16 rows (wave 0 only) ----
    if (wave == 0) {
        const int m = lane & 15;
        const int koff = (lane >> 4) * 8;
        f32x4 acc[4];
#pragma unroll
        for (int c = 0; c < 4; c++) acc[c] = (f32x4){0.f, 0.f, 0.f, 0.f};
#pragma unroll
        for (int kg = 0; kg < 8; kg++) {
            f16x8 a = *(const f16x8*)&hc[m][kg * 32 + koff];
#pragma unroll
            for (int nt = 0; nt < 4; nt++) {
                const size_t bidx = (size_t)(((nt << 3) + kg) * 64 + lane) * 8;
                f16x8 bfr = *(const f16x8*)(B2 + bidx);
                acc[nt] = __builtin_amdgcn_mfma_f32_16x16x32_f16(a, bfr, acc[nt], 0, 0, 0);
            }
        }
        const int row0 = blockIdx.x * 16;
        const int rbase = (lane >> 4) * 4;
        const int colq = lane & 15;
        float s1a[4] = {0.f, 0.f, 0.f, 0.f}, s2a[4] = {0.f, 0.f, 0.f, 0.f};
#pragma unroll
        for (int nt = 0; nt < 4; nt++) {
            const int col = nt * 16 + colq;
            const float a1v = attnO[col];
            const float a2v = attnO[64 + col];
#pragma unroll
            for (int r = 0; r < 4; r++) {
                float c = acc[nt][r];
                int row = row0 + rbase + r;
                if (row < N) H2[(size_t)row * 64 + col] = (f16)c;
                s1a[r] += c * a1v;
                s2a[r] += c * a2v;
            }
        }
#pragma unroll
        for (int off = 1; off < 16; off <<= 1)
#pragma unroll
            for (int r = 0; r < 4; r++) {
                s1a[r] += __shfl_xor(s1a[r], off);
                s2a[r] += __shfl_xor(s2a[r], off);
            }
        if (colq == 0)
#pragma unroll
            for (int r = 0; r < 4; r++) {
                int row = row0 + rbase + r;
                if (row < N) { s1b[row] = s1a[r]; s2b[row] = s2a[r]; }
            }
    }
}

// ---------------- layer-2 aggregate: paired gather, no-max softmax ----------------
__global__ __launch_bounds__(256) void agg_l2(const int* __restrict__ rowst, const int* __restrict__ cnt,
                                              const int* __restrict__ edged,
                                              const float* __restrict__ s1, const float* __restrict__ s2,
                                              const f16* __restrict__ H, float* __restrict__ outp, int N) {
    __shared__ float wls[4][64];
    __shared__ int dls[4][64];
    const int t = threadIdx.x, lane = t & 63, wave = t >> 6;
    const int node = blockIdx.x * 4 + wave;
    if (node >= N) return;
    const int beg = rowst[node];
    const int deg = cnt[node];
    const int end = beg + deg;
    if (deg == 0) { outp[(size_t)node * 64 + lane] = 0.f; return; }
    const float s1v = s1[node];

    if (deg <= 64) {
        int d = 0;
        if (lane < deg) d = edged[beg + lane];
        dls[wave][lane] = d;
        float sc = nlrelu(s1v + s2[d]);
        float ex = (lane < deg) ? __expf(sc) : 0.f;
        float sm = ex;
#pragma unroll
        for (int off = 32; off > 0; off >>= 1) sm += __shfl_xor(sm, off);
        wls[wave][lane] = ex / sm;
        const int h2 = lane >> 5;
        const int p = lane & 31;
        float ax = 0.f, ay = 0.f;
        for (int e = 0; e < deg; e += 2) {
            int ei = e + h2;
            float w = wls[wave][ei];
            int dd = dls[wave][ei];
            unsigned raw = *(const unsigned*)(H + (size_t)dd * 64 + p * 2);
            f16x2 hv = __builtin_bit_cast(f16x2, raw);
            ax += w * (float)hv[0];
            ay += w * (float)hv[1];
        }
        ax += __shfl_xor(ax, 32);
        ay += __shfl_xor(ay, 32);
        if (lane < 32) *(float2*)(outp + (size_t)node * 64 + p * 2) = make_float2(ax, ay);
    } else {
        float sm = 0.f;
        for (int e = beg + lane; e < end; e += 64) {
            int d = edged[e];
            sm += __expf(nlrelu(s1v + s2[d]));
        }
#pragma unroll
        for (int off = 32; off > 0; off >>= 1) sm += __shfl_xor(sm, off);
        float inv = 1.f / sm;
        float acc = 0.f;
        for (int e = beg; e < end; e++) {
            int dd = edged[e];
            float w = __expf(nlrelu(s1v + s2[dd])) * inv;
            acc += w * (float)H[(size_t)dd * 64 + lane];
        }
        outp[(size_t)node * 64 + lane] = acc;
    }
}

extern "C" void kernel_launch(void* const* d_in, const int* in_sizes, int n_in,
                              void* d_out, int out_size, void* d_ws, size_t ws_size,
                              hipStream_t stream) {
    const float* x     = (const float*)d_in[0];
    const int*   ei    = (const int*)d_in[1];     // [2][E] int32
    const float* Wh    = (const float*)d_in[2];
    const float* attnH = (const float*)d_in[3];
    const float* Wo    = (const float*)d_in[4];
    const float* attnO = (const float*)d_in[5];
    float* out         = (float*)d_out;

    const int N = in_sizes[0] / 128;    // 50000
    const int E = in_sizes[1] / 2;      // 800000
    const int* srcp = ei;
    const int* dstp = ei + E;

    char* base = (char*)d_ws;
    size_t off = 0;
    auto take = [&](size_t b) { void* p = base + off; off += (b + 255) & ~(size_t)255; return p; };
    f16*   B1     = (f16*)  take(32768 * 2);
    f16*   B2     = (f16*)  take(16384 * 2);
    int*   counts = (int*)  take((size_t)N * 4);
    int*   rowst  = (int*)  take((size_t)N * 4);
    int*   pos    = (int*)  take((size_t)E * 4);
    int*   edged  = (int*)  take((size_t)E * 4);
    int*   cursor = (int*)  take(256);
    float* s1     = (float*)take((size_t)N * 4 * 4);
    float* s2     = (float*)take((size_t)N * 4 * 4);
    float* s1b    = (float*)take((size_t)N * 4);
    float* s2b    = (float*)take((size_t)N * 4);
    f16*   H1     = (f16*)  take((size_t)N * 256 * 2);
    f16*   H2     = (f16*)  take((size_t)N * 64 * 2);

    hipMemsetAsync(counts, 0, (size_t)N * 4, stream);

    const int eb4 = (E + 1023) / 1024;
    k_initcnt<<<192 + eb4, 256, 0, stream>>>(Wh, Wo, B1, B2, srcp, counts, pos, cursor, E, N);

    const int nb = (N + 1023) / 1024;
    scan_ticket<<<nb, 1024, 0, stream>>>(counts, rowst, cursor, N);

    const int Gs = eb4;                  // scatter blocks (first — long pole)
    const int Gg = (N + 63) / 64;        // gemm1 blocks
    k_scatg1<<<Gs + Gg, 256, 0, stream>>>(srcp, dstp, rowst, pos, edged,
                                          x, B1, attnH, H1, s1, s2, N, E, N, Gs);

    agg1g2<<<(N + 15) / 16, 256, 0, stream>>>(rowst, counts, edged, s1, s2, H1,
                                              B2, attnO, H2, s1b, s2b, N);

    agg_l2<<<(N + 3) / 4, 256, 0, stream>>>(rowst, counts, edged, s1b, s2b, H2, out, N);
}